// Round 15
// baseline (54.964 us; speedup 1.0000x reference)
//
#include <hip/hip_runtime.h>
#include <hip/hip_bf16.h>

// Problem constants
#define NB 4
#define SEQ 2048
#define DM 1024
#define DH 64

typedef __attribute__((ext_vector_type(8))) short bf16x8;
typedef __attribute__((ext_vector_type(4))) float f32x4;
typedef __attribute__((ext_vector_type(4))) short short4v;

__device__ inline short f2bf(float f) {
  union { float f; unsigned u; } x; x.f = f;
  unsigned r = x.u + 0x7FFFu + ((x.u >> 16) & 1u);
  return (short)(r >> 16);
}

__device__ inline void gload_lds16(const short* g, short* l) {
  __builtin_amdgcn_global_load_lds(
      (const __attribute__((address_space(1))) void*)g,
      (__attribute__((address_space(3))) void*)l, 16, 0, 0);
}

// ---------------------------------------------------------------------------
// Kernel 0: W fp32 -> bf16, PRE-SWIZZLED (T21): within each 8-chunk (128B)
// group, chunk c of row r is stored at position c^(r&7). gload_lds then
// copies linearly into LDS and the frag-read applies the same XOR ->
// conflict-free b128 reads. wbf rows: 0-63 Wq, 64-127 Wk, 128-191 Wv.
// ---------------------------------------------------------------------------
__global__ __launch_bounds__(256) void wconv_kernel(
    const float* __restrict__ Wq, const float* __restrict__ Wk,
    const float* __restrict__ Wv, short* __restrict__ wbf)
{
  const int tid = blockIdx.x * 256 + threadIdx.x;
  const int base = tid * 8;            // bf16 element index
  const int row = base >> 10;          // 0..191
  const int col = base & 1023;
  const float* src = (row < 64) ? Wq : (row < 128) ? Wk : Wv;
  src += (size_t)(row & 63) * DM + col;
  f32x4 f0 = ((const f32x4*)src)[0];
  f32x4 f1 = ((const f32x4*)src)[1];
  bf16x8 h = { f2bf(f0[0]), f2bf(f0[1]), f2bf(f0[2]), f2bf(f0[3]),
               f2bf(f1[0]), f2bf(f1[1]), f2bf(f1[2]), f2bf(f1[3]) };
  const int c16 = col >> 3;            // 16B chunk index 0..127
  const int c16s = (c16 & ~7) | ((c16 ^ row) & 7);   // swizzled position
  *(bf16x8*)(wbf + (size_t)row * DM + c16s * 8) = h;
}

// ---------------------------------------------------------------------------
// Kernel 1 (v4, T21): QKV projection. Grid (256 M-tiles x 2 N-halves) x 256
// threads (4 waves) -> 512 blocks = 2/CU. Tile 32 rows x 96 cols, BK=64,
// 16 iters. W staged via global_load_lds (linear LDS, pre-swizzled source);
// X reg-staged with swizzled ds_write. One barrier per iter; W prefetch
// issued before compute (m97 2-barrier shape).
// ---------------------------------------------------------------------------
__global__ __launch_bounds__(256) void proj_kernel(
    const float* __restrict__ X, const short* __restrict__ wbf,
    short* __restrict__ qout, short* __restrict__ kout,
    short* __restrict__ vtout)
{
  __shared__ short w_lds[2][96 * 64];   // 12KB per buf, linear
  __shared__ short x_lds[2][32 * 64];   //  4KB per buf, swizzled layout

  const int t = threadIdx.x;
  const int l = t & 63;
  const int w = t >> 6;                 // wave 0..3
  const int m0 = blockIdx.x * 32;
  const int h  = blockIdx.y;            // N-half (96 cols)

  const int mw = w & 1;                 // M-frag of this wave
  const int ng = w >> 1;                // N-group (3 frags each)

  f32x4 acc[3];
#pragma unroll
  for (int i = 0; i < 3; i++) acc[i] = (f32x4){0.f, 0.f, 0.f, 0.f};

  // X staging geometry: thread t -> row t>>3 (0..31), chunk t&7 (32B fp32)
  const int xrow = t >> 3;
  const int xch  = t & 7;
  const float* xsrc = X + (size_t)(m0 + xrow) * DM + xch * 8;
  const int xdst = xrow * 64 + ((xch ^ (xrow & 7)) << 3);  // swizzled shorts

  // W staging geometry (gload_lds): wave-uniform LDS base (w*3+i)*512 shorts,
  // lane l copies chunk c=(w*3+i)*64+l: row=c>>3, in-row chunk=c&7.
  // Source is PRE-SWIZZLED wbf -> linear read matches swizzled layout.
  const short* wsrc_base = wbf + (size_t)h * 96 * DM;

  // ---- prologue: stage k-step 0 into buf0 ----
#pragma unroll
  for (int i = 0; i < 3; i++) {
    const int c = (w * 3 + i) * 64 + l;
    const short* g = wsrc_base + (size_t)(c >> 3) * DM + (c & 7) * 8;
    gload_lds16(g, &w_lds[0][(w * 3 + i) * 512]);
  }
  {
    f32x4 f0 = ((const f32x4*)xsrc)[0];
    f32x4 f1 = ((const f32x4*)xsrc)[1];
    bf16x8 hx = { f2bf(f0[0]), f2bf(f0[1]), f2bf(f0[2]), f2bf(f0[3]),
                  f2bf(f1[0]), f2bf(f1[1]), f2bf(f1[2]), f2bf(f1[3]) };
    *(bf16x8*)&x_lds[0][xdst] = hx;
  }
  __syncthreads();

  for (int it = 0; it < 16; it++) {
    const int buf = it & 1;
    const bool pf = (it < 15);
    const int k1 = (it + 1) * 64;

    // issue next tile's W gload_lds + X loads BEFORE compute
    f32x4 f0, f1;
    if (pf) {
#pragma unroll
      for (int i = 0; i < 3; i++) {
        const int c = (w * 3 + i) * 64 + l;
        const short* g = wsrc_base + (size_t)(c >> 3) * DM + k1 + (c & 7) * 8;
        gload_lds16(g, &w_lds[buf ^ 1][(w * 3 + i) * 512]);
      }
      f0 = ((const f32x4*)(xsrc + k1))[0];
      f1 = ((const f32x4*)(xsrc + k1))[1];
    }

    // compute from buf: A-frag row mw*16+(l&15); chunks (l>>4) and (l>>4)+4,
    // XOR-deswizzled per row.
    {
      const int arow = mw * 16 + (l & 15);
      const int ac = l >> 4;
      bf16x8 a0 = *(const bf16x8*)&x_lds[buf][arow * 64 + ((ac ^ (arow & 7)) << 3)];
      bf16x8 a1 = *(const bf16x8*)&x_lds[buf][arow * 64 + (((ac + 4) ^ (arow & 7)) << 3)];
#pragma unroll
      for (int j = 0; j < 3; j++) {
        const int wrow = (ng * 3 + j) * 16 + (l & 15);
        bf16x8 b0 = *(const bf16x8*)&w_lds[buf][wrow * 64 + ((ac ^ (wrow & 7)) << 3)];
        bf16x8 b1 = *(const bf16x8*)&w_lds[buf][wrow * 64 + (((ac + 4) ^ (wrow & 7)) << 3)];
        acc[j] = __builtin_amdgcn_mfma_f32_16x16x32_bf16(a0, b0, acc[j], 0, 0, 0);
        acc[j] = __builtin_amdgcn_mfma_f32_16x16x32_bf16(a1, b1, acc[j], 0, 0, 0);
      }
    }

    // X convert + swizzled ds_write after compute (loads had compute cover)
    if (pf) {
      bf16x8 hx = { f2bf(f0[0]), f2bf(f0[1]), f2bf(f0[2]), f2bf(f0[3]),
                    f2bf(f1[0]), f2bf(f1[1]), f2bf(f1[2]), f2bf(f1[3]) };
      *(bf16x8*)&x_lds[buf ^ 1][xdst] = hx;
    }
    __syncthreads();
  }

  // epilogue: C row=(lane>>4)*4+reg, col=cf*16+(lane&15)  [m89]
  const int rowb = m0 + mw * 16 + ((l >> 4) << 2);
#pragma unroll
  for (int j = 0; j < 3; j++) {
    const int c = h * 96 + (ng * 3 + j) * 16 + (l & 15);
#pragma unroll
    for (int jj = 0; jj < 4; jj++) {
      const int row = rowb + jj;
      const float v = acc[j][jj];
      if (c < 64) {
        qout[row * DH + c] = f2bf(v * 0.03125f);  // fold 1/sqrt(1024)=1/32
      } else if (c < 128) {
        kout[row * DH + (c - 64)] = f2bf(v);
      } else {
        const int b = row >> 11, s = row & (SEQ - 1);
        vtout[b * (DH * SEQ) + (c - 128) * SEQ + s] = f2bf(v);
      }
    }
  }
}

// ---------------------------------------------------------------------------
// Kernel 2: split-KV causal flash (R9 verbatim; run at nck=4/cht=8).
// ---------------------------------------------------------------------------
__global__ __launch_bounds__(256) void flash_kernel(
    const short* __restrict__ qin, const short* __restrict__ kin,
    const short* __restrict__ vtin, float* __restrict__ po,
    float* __restrict__ pm, float* __restrict__ pl,
    const int nck, const int cht)
{
  __shared__ short k_lds[2][64][72];
  __shared__ short vt_lds[2][64][72];
  __shared__ short p_lds[4][16][72];

  const int qt = blockIdx.x;
  const int ck = blockIdx.y;
  const int t0 = ck * cht;
  if (t0 > qt) return;
  const int b = blockIdx.z;

  const int t = threadIdx.x;
  const int l = t & 63;
  const int w = t >> 6;
  const int q0 = qt * 64;
  const int tend = min(t0 + cht, qt + 1);

  const short* qb = qin  + (size_t)b * SEQ * DH;
  const short* kb = kin  + (size_t)b * SEQ * DH;
  const short* vb = vtin + (size_t)b * DH * SEQ;

  const short* qr = qb + (size_t)(q0 + w * 16 + (l & 15)) * DH + ((l >> 4) << 3);
  const bf16x8 qf0 = *(const bf16x8*)qr;
  const bf16x8 qf1 = *(const bf16x8*)(qr + 32);

  f32x4 o[4];
#pragma unroll
  for (int i = 0; i < 4; i++) o[i] = (f32x4){0.f, 0.f, 0.f, 0.f};
  float m_run[4] = {-1e30f, -1e30f, -1e30f, -1e30f};
  float l_run[4] = {0.f, 0.f, 0.f, 0.f};

  const int sr = t >> 3;
  const int sc = (t & 7) * 8;

  {
    const int j0 = t0 * 64;
#pragma unroll
    for (int i = 0; i < 2; i++) {
      const int r = sr + i * 32;
      *(bf16x8*)&k_lds[0][r][sc]  = *(const bf16x8*)(kb + (size_t)(j0 + r) * DH + sc);
      *(bf16x8*)&vt_lds[0][r][sc] = *(const bf16x8*)(vb + (size_t)r * SEQ + j0 + sc);
    }
  }
  __syncthreads();

  for (int tt = t0; tt < tend; tt++) {
    const int bi = (tt - t0) & 1;
    const int j0 = tt * 64;
    const bool pf = (tt + 1 < tend);

    bf16x8 kpf0, kpf1, vpf0, vpf1;
    if (pf) {
      const int j1 = j0 + 64;
      kpf0 = *(const bf16x8*)(kb + (size_t)(j1 + sr) * DH + sc);
      kpf1 = *(const bf16x8*)(kb + (size_t)(j1 + sr + 32) * DH + sc);
      vpf0 = *(const bf16x8*)(vb + (size_t)sr * SEQ + j1 + sc);
      vpf1 = *(const bf16x8*)(vb + (size_t)(sr + 32) * SEQ + j1 + sc);
    }

    f32x4 s[4];
#pragma unroll
    for (int nf = 0; nf < 4; nf++) {
      const short* kr = &k_lds[bi][nf * 16 + (l & 15)][(l >> 4) << 3];
      bf16x8 b0 = *(const bf16x8*)kr;
      bf16x8 b1 = *(const bf16x8*)(kr + 32);
      f32x4 a = (f32x4){0.f, 0.f, 0.f, 0.f};
      a = __builtin_amdgcn_mfma_f32_16x16x32_bf16(qf0, b0, a, 0, 0, 0);
      a = __builtin_amdgcn_mfma_f32_16x16x32_bf16(qf1, b1, a, 0, 0, 0);
      s[nf] = a;
    }

    {
      const int growb = q0 + w * 16 + ((l >> 4) << 2);
#pragma unroll
      for (int nf = 0; nf < 4; nf++) {
        const int gcol = j0 + nf * 16 + (l & 15);
#pragma unroll
        for (int j = 0; j < 4; j++)
          if (gcol > growb + j) s[nf][j] = -1e30f;
      }
    }

    float alpha[4];
#pragma unroll
    for (int j = 0; j < 4; j++) {
      float tm = fmaxf(fmaxf(s[0][j], s[1][j]), fmaxf(s[2][j], s[3][j]));
      tm = fmaxf(tm, __shfl_xor(tm, 1));
      tm = fmaxf(tm, __shfl_xor(tm, 2));
      tm = fmaxf(tm, __shfl_xor(tm, 4));
      tm = fmaxf(tm, __shfl_xor(tm, 8));
      const float mn = fmaxf(m_run[j], tm);
      alpha[j] = exp2f((m_run[j] - mn) * 1.44269504f);
      m_run[j] = mn;
      float rs = 0.f;
#pragma unroll
      for (int nf = 0; nf < 4; nf++) {
        const float p = exp2f((s[nf][j] - mn) * 1.44269504f);
        s[nf][j] = p;
        rs += p;
      }
      rs += __shfl_xor(rs, 1);
      rs += __shfl_xor(rs, 2);
      rs += __shfl_xor(rs, 4);
      rs += __shfl_xor(rs, 8);
      l_run[j] = l_run[j] * alpha[j] + rs;
    }
#pragma unroll
    for (int df = 0; df < 4; df++)
#pragma unroll
      for (int j = 0; j < 4; j++) o[df][j] *= alpha[j];

#pragma unroll
    for (int nf = 0; nf < 4; nf++)
#pragma unroll
      for (int j = 0; j < 4; j++)
        p_lds[w][((l >> 4) << 2) + j][nf * 16 + (l & 15)] = f2bf(s[nf][j]);

    asm volatile("s_waitcnt lgkmcnt(0)" ::: "memory");
    __builtin_amdgcn_sched_barrier(0);

#pragma unroll
    for (int ks = 0; ks < 2; ks++) {
      const short* pr = &p_lds[w][l & 15][ks * 32 + ((l >> 4) << 3)];
      const bf16x8 pa = *(const bf16x8*)pr;
#pragma unroll
      for (int df = 0; df < 4; df++) {
        const short* vr = &vt_lds[bi][df * 16 + (l & 15)][ks * 32 + ((l >> 4) << 3)];
        const bf16x8 vf = *(const bf16x8*)vr;
        o[df] = __builtin_amdgcn_mfma_f32_16x16x32_bf16(pa, vf, o[df], 0, 0, 0);
      }
    }

    if (pf) {
      *(bf16x8*)&k_lds[bi ^ 1][sr][sc]       = kpf0;
      *(bf16x8*)&k_lds[bi ^ 1][sr + 32][sc]  = kpf1;
      *(bf16x8*)&vt_lds[bi ^ 1][sr][sc]      = vpf0;
      *(bf16x8*)&vt_lds[bi ^ 1][sr + 32][sc] = vpf1;
    }
    __syncthreads();
  }

  const int rowb = q0 + w * 16 + ((l >> 4) << 2);
#pragma unroll
  for (int j = 0; j < 4; j++) {
    const size_t rowg = (size_t)b * SEQ + rowb + j;
#pragma unroll
    for (int df = 0; df < 4; df++)
      po[(rowg * nck + ck) * DH + df * 16 + (l & 15)] = o[df][j];
    if ((l & 15) == 0) {
      pm[rowg * nck + ck] = m_run[j];
      pl[rowg * nck + ck] = l_run[j];
    }
  }
}

// ---------------------------------------------------------------------------
// Kernel 3: merge partials (unchanged). ckshift = log2(cht*64).
// ---------------------------------------------------------------------------
__global__ __launch_bounds__(256) void merge_kernel(
    const float* __restrict__ po, const float* __restrict__ pm,
    const float* __restrict__ pl, float* __restrict__ out,
    const int nck, const int ckshift)
{
  const int gid = blockIdx.x * 256 + threadIdx.x;
  const int r = gid >> 6;
  const int d = gid & 63;
  const int s = r & (SEQ - 1);
  const int C = (s >> ckshift) + 1;

  float m = -1e30f;
  for (int c = 0; c < C; c++) m = fmaxf(m, pm[r * nck + c]);
  float den = 0.f, num = 0.f;
  for (int c = 0; c < C; c++) {
    const float wgt = exp2f((pm[r * nck + c] - m) * 1.44269504f);
    den += pl[r * nck + c] * wgt;
    num += po[(size_t)(r * nck + c) * DH + d] * wgt;
  }
  out[gid] = num / den;
}

extern "C" void kernel_launch(void* const* d_in, const int* in_sizes, int n_in,
                              void* d_out, int out_size, void* d_ws, size_t ws_size,
                              hipStream_t stream) {
  const float* X  = (const float*)d_in[0];
  const float* Wq = (const float*)d_in[1];
  const float* Wk = (const float*)d_in[2];
  const float* Wv = (const float*)d_in[3];

  const size_t nrow = (size_t)NB * SEQ;              // 8192
  short* qws  = (short*)d_ws;                        // [8192][64] bf16
  short* kws  = qws + nrow * DH;
  short* vtws = kws + nrow * DH;
  const size_t qkv_bytes = 3 * nrow * DH * sizeof(short);   // 3.15 MB

  // layout: qkv | po [8192][nck][64] f32 | pm | pl   (wbf aliases po start;
  // wbf is dead before flash overwrites it)
  int nck, cht, ckshift;
  {
    const size_t need4 = qkv_bytes + nrow * 4 * (DH + 2) * sizeof(float);
    if (ws_size >= need4) { nck = 4; cht = 8;  ckshift = 9;  }
    else                  { nck = 1; cht = 32; ckshift = 11; }
  }
  float* po  = (float*)(vtws + nrow * DH);
  short* wbf = (short*)po;
  float* pm  = po + nrow * nck * DH;
  float* pl  = pm + nrow * nck;

  wconv_kernel<<<dim3(96), 256, 0, stream>>>(Wq, Wk, Wv, wbf);
  proj_kernel<<<dim3(256, 2), 256, 0, stream>>>(X, wbf, qws, kws, vtws);
  flash_kernel<<<dim3(SEQ / 64, nck, NB), 256, 0, stream>>>(qws, kws, vtws, po, pm, pl, nck, cht);
  merge_kernel<<<dim3(NB * SEQ * DH / 256), 256, 0, stream>>>(po, pm, pl, (float*)d_out, nck, ckshift);
}

// Round 17
// 54.483 us; speedup vs baseline: 1.0088x; 1.0088x over previous
//
#include <hip/hip_runtime.h>
#include <hip/hip_bf16.h>

// Problem constants
#define NB 4
#define SEQ 2048
#define DM 1024
#define DH 64

typedef __attribute__((ext_vector_type(8))) short bf16x8;
typedef __attribute__((ext_vector_type(4))) float f32x4;
typedef __attribute__((ext_vector_type(4))) short short4v;

__device__ inline short f2bf(float f) {
  union { float f; unsigned u; } x; x.f = f;
  unsigned r = x.u + 0x7FFFu + ((x.u >> 16) & 1u);
  return (short)(r >> 16);
}

__device__ inline float bf2f(short s) {
  union { unsigned u; float f; } x;
  x.u = ((unsigned)(unsigned short)s) << 16;
  return x.f;
}

// ---------------------------------------------------------------------------
// Kernel 0: W fp32 -> bf16, once. wbf[192][1024] row-major: rows 0-63 Wq,
// 64-127 Wk, 128-191 Wv.
// ---------------------------------------------------------------------------
__global__ __launch_bounds__(256) void wconv_kernel(
    const float* __restrict__ Wq, const float* __restrict__ Wk,
    const float* __restrict__ Wv, short* __restrict__ wbf)
{
  const int tid = blockIdx.x * 256 + threadIdx.x;
  const int base = tid * 8;
  const int row = base >> 10;          // 0..191
  const int col = base & 1023;
  const float* src = (row < 64) ? Wq : (row < 128) ? Wk : Wv;
  src += (size_t)(row & 63) * DM + col;
  f32x4 f0 = ((const f32x4*)src)[0];
  f32x4 f1 = ((const f32x4*)src)[1];
  bf16x8 h = { f2bf(f0[0]), f2bf(f0[1]), f2bf(f0[2]), f2bf(f0[3]),
               f2bf(f1[0]), f2bf(f1[1]), f2bf(f1[2]), f2bf(f1[3]) };
  *(bf16x8*)(wbf + (size_t)row * DM + col) = h;
}

// ---------------------------------------------------------------------------
// Kernel 1 (v5): BARRIER-FREE QKV projection. Grid (64 M-blocks, 4 K-quarters)
// x 512 threads (8 waves). W-quarter [192][256] bf16 = 96KB loaded to LDS
// ONCE (single barrier), XOR-swizzled chunks (2-lane/bank frag reads). Then
// each wave independently streams its 16 M-rows: A-frags DIRECT from global
// X (fp32 -> cvt_pk bf16 in regs, no X LDS), 12 N-frags x 8 K-steps, ZERO
// barriers in the K-loop. Writes bf16 partials pacc[4][8192][192].
// ---------------------------------------------------------------------------
__global__ __launch_bounds__(512) void proj_v5_kernel(
    const float* __restrict__ X, const short* __restrict__ wbf,
    short* __restrict__ pacc)
{
  __shared__ short w_lds[192 * 256];    // 96 KB

  const int t = threadIdx.x;
  const int l = t & 63;
  const int w = t >> 6;                 // 0..7
  const int ks = blockIdx.y;            // K-quarter
  const int kbase = ks * 256;
  const int m0 = blockIdx.x * 128;

  // ---- load W quarter once (12 chunks of 16B per thread), swizzled ----
#pragma unroll
  for (int i = 0; i < 12; i++) {
    const int idx = t + i * 512;        // 0..6143
    const int row = idx >> 5;           // 0..191 (32 chunks/row)
    const int c = idx & 31;
    bf16x8 v = *(const bf16x8*)(wbf + (size_t)row * DM + kbase + c * 8);
    const int cs = (c & ~7) | ((c ^ row) & 7);
    *(bf16x8*)&w_lds[row * 256 + cs * 8] = v;
  }
  __syncthreads();                      // the ONLY barrier

  f32x4 acc[12];
#pragma unroll
  for (int i = 0; i < 12; i++) acc[i] = (f32x4){0.f, 0.f, 0.f, 0.f};

  // A-frag source: lane l owns row m0 + w*16 + (l&15), k-part (l>>4)*8
  const float* xrow = X + (size_t)(m0 + w * 16 + (l & 15)) * DM
                        + kbase + ((l >> 4) << 3);

  // K-loop: 8 steps of BK=32, no syncs — waves fully independent
#pragma unroll
  for (int k8 = 0; k8 < 8; k8++) {
    f32x4 xa0 = *(const f32x4*)(xrow + k8 * 32);
    f32x4 xa1 = *(const f32x4*)(xrow + k8 * 32 + 4);
    bf16x8 a = { f2bf(xa0[0]), f2bf(xa0[1]), f2bf(xa0[2]), f2bf(xa0[3]),
                 f2bf(xa1[0]), f2bf(xa1[1]), f2bf(xa1[2]), f2bf(xa1[3]) };
    const int c = k8 * 4 + (l >> 4);    // 16B chunk index 0..31
#pragma unroll
    for (int nf = 0; nf < 12; nf++) {
      const int row = nf * 16 + (l & 15);
      const int cs = (c & ~7) | ((c ^ row) & 7);
      bf16x8 b = *(const bf16x8*)&w_lds[row * 256 + cs * 8];
      acc[nf] = __builtin_amdgcn_mfma_f32_16x16x32_bf16(a, b, acc[nf], 0, 0, 0);
    }
  }

  // epilogue: bf16 partials. C row=(l>>4)*4+j, col=nf*16+(l&15)  [m89]
  short* pp = pacc + (size_t)ks * (NB * SEQ) * 192;
  const int rowb = m0 + w * 16 + ((l >> 4) << 2);
#pragma unroll
  for (int nf = 0; nf < 12; nf++) {
    const int c = nf * 16 + (l & 15);
#pragma unroll
    for (int j = 0; j < 4; j++)
      pp[(size_t)(rowb + j) * 192 + c] = f2bf(acc[nf][j]);
  }
}

// ---------------------------------------------------------------------------
// Kernel 1b: reduce 4 K-split partials, route to q (x1/32), k, vt.
// (R11-proven.)
// ---------------------------------------------------------------------------
__global__ __launch_bounds__(256) void reduce4_kernel(
    const short* __restrict__ pacc, short* __restrict__ qout,
    short* __restrict__ kout, short* __restrict__ vtout)
{
  const int gid = blockIdx.x * 256 + threadIdx.x;   // 0 .. 8192*48-1
  const int r = gid / 48;
  const int cg = gid - r * 48;
  const int c0 = cg * 4;

  float v0 = 0.f, v1 = 0.f, v2 = 0.f, v3 = 0.f;
#pragma unroll
  for (int s = 0; s < 4; s++) {
    const short4v a = *(const short4v*)(pacc + ((size_t)s * (NB * SEQ) + r) * 192 + c0);
    v0 += bf2f(a[0]); v1 += bf2f(a[1]); v2 += bf2f(a[2]); v3 += bf2f(a[3]);
  }

  if (c0 < 64) {
    short4v h = { f2bf(v0 * 0.03125f), f2bf(v1 * 0.03125f),
                  f2bf(v2 * 0.03125f), f2bf(v3 * 0.03125f) };
    *(short4v*)(qout + (size_t)r * DH + c0) = h;
  } else if (c0 < 128) {
    short4v h = { f2bf(v0), f2bf(v1), f2bf(v2), f2bf(v3) };
    *(short4v*)(kout + (size_t)r * DH + (c0 - 64)) = h;
  } else {
    const int bb = r >> 11, s = r & (SEQ - 1);
    short* vt = vtout + (size_t)bb * DH * SEQ + (size_t)(c0 - 128) * SEQ + s;
    vt[0 * SEQ] = f2bf(v0);
    vt[1 * SEQ] = f2bf(v1);
    vt[2 * SEQ] = f2bf(v2);
    vt[3 * SEQ] = f2bf(v3);
  }
}

// ---------------------------------------------------------------------------
// Fallback proj (R9 verbatim): used only if ws too small for pacc.
// ---------------------------------------------------------------------------
__global__ __launch_bounds__(512) void proj_fb_kernel(
    const float* __restrict__ X, const short* __restrict__ wbf,
    short* __restrict__ qout, short* __restrict__ kout,
    short* __restrict__ vtout)
{
  __shared__ short x_lds[2][32][72];
  __shared__ short w_lds[2][192][72];

  const int t = threadIdx.x;
  const int l = t & 63;
  const int w = t >> 6;
  const int m0 = blockIdx.x * 32;

  f32x4 acc[3];
#pragma unroll
  for (int i = 0; i < 3; i++) acc[i] = (f32x4){0.f, 0.f, 0.f, 0.f};

  const int xr = t >> 4;
  const int xc = (t & 15) * 4;
  const int wr = t >> 3;
  const int wc = (t & 7) * 8;

  const float* xsrc  = X   + (size_t)(m0 + xr) * DM + xc;
  const short* wsrc0 = wbf + (size_t)(wr)       * DM + wc;
  const short* wsrc1 = wbf + (size_t)(64 + wr)  * DM + wc;
  const short* wsrc2 = wbf + (size_t)(128 + wr) * DM + wc;

  {
    f32x4 f = *(const f32x4*)xsrc;
    short4v h = { f2bf(f[0]), f2bf(f[1]), f2bf(f[2]), f2bf(f[3]) };
    *(short4v*)&x_lds[0][xr][xc] = h;
    *(bf16x8*)&w_lds[0][wr][wc]       = *(const bf16x8*)wsrc0;
    *(bf16x8*)&w_lds[0][64 + wr][wc]  = *(const bf16x8*)wsrc1;
    *(bf16x8*)&w_lds[0][128 + wr][wc] = *(const bf16x8*)wsrc2;
  }
  f32x4 xA = *(const f32x4*)(xsrc + 64);
  bf16x8 wA0 = *(const bf16x8*)(wsrc0 + 64);
  bf16x8 wA1 = *(const bf16x8*)(wsrc1 + 64);
  bf16x8 wA2 = *(const bf16x8*)(wsrc2 + 64);
  f32x4 xB;
  bf16x8 wB0, wB1, wB2;
  __syncthreads();

#pragma unroll
  for (int it = 0; it < 16; it++) {
    const int buf = it & 1;
    const int k2 = (it + 2) * 64;

    if ((it & 1) == 0) {
      if (it + 2 < 16) {
        xB  = *(const f32x4*)(xsrc + k2);
        wB0 = *(const bf16x8*)(wsrc0 + k2);
        wB1 = *(const bf16x8*)(wsrc1 + k2);
        wB2 = *(const bf16x8*)(wsrc2 + k2);
      }
    } else {
      if (it + 2 < 16) {
        xA  = *(const f32x4*)(xsrc + k2);
        wA0 = *(const bf16x8*)(wsrc0 + k2);
        wA1 = *(const bf16x8*)(wsrc1 + k2);
        wA2 = *(const bf16x8*)(wsrc2 + k2);
      }
    }

    const short* xp = &x_lds[buf][(w & 1) * 16 + (l & 15)][(l >> 4) << 3];
    bf16x8 a0 = *(const bf16x8*)xp;
    bf16x8 a1 = *(const bf16x8*)(xp + 32);
#pragma unroll
    for (int nf = 0; nf < 3; nf++) {
      const int cf = (w >> 1) * 3 + nf;
      const short* wp = &w_lds[buf][cf * 16 + (l & 15)][(l >> 4) << 3];
      bf16x8 b0 = *(const bf16x8*)wp;
      bf16x8 b1 = *(const bf16x8*)(wp + 32);
      acc[nf] = __builtin_amdgcn_mfma_f32_16x16x32_bf16(a0, b0, acc[nf], 0, 0, 0);
      acc[nf] = __builtin_amdgcn_mfma_f32_16x16x32_bf16(a1, b1, acc[nf], 0, 0, 0);
    }

    if (it < 15) {
      if ((it & 1) == 0) {
        short4v h = { f2bf(xA[0]), f2bf(xA[1]), f2bf(xA[2]), f2bf(xA[3]) };
        *(short4v*)&x_lds[buf ^ 1][xr][xc] = h;
        *(bf16x8*)&w_lds[buf ^ 1][wr][wc]       = wA0;
        *(bf16x8*)&w_lds[buf ^ 1][64 + wr][wc]  = wA1;
        *(bf16x8*)&w_lds[buf ^ 1][128 + wr][wc] = wA2;
      } else {
        short4v h = { f2bf(xB[0]), f2bf(xB[1]), f2bf(xB[2]), f2bf(xB[3]) };
        *(short4v*)&x_lds[buf ^ 1][xr][xc] = h;
        *(bf16x8*)&w_lds[buf ^ 1][wr][wc]       = wB0;
        *(bf16x8*)&w_lds[buf ^ 1][64 + wr][wc]  = wB1;
        *(bf16x8*)&w_lds[buf ^ 1][128 + wr][wc] = wB2;
      }
    }
    __syncthreads();
  }

  const int rowb = m0 + (w & 1) * 16 + ((l >> 4) << 2);
#pragma unroll
  for (int nf = 0; nf < 3; nf++) {
    const int c = ((w >> 1) * 3 + nf) * 16 + (l & 15);
#pragma unroll
    for (int j = 0; j < 4; j++) {
      const int row = rowb + j;
      const float v = acc[nf][j];
      if (c < 64) {
        qout[row * DH + c] = f2bf(v * 0.03125f);
      } else if (c < 128) {
        kout[row * DH + (c - 64)] = f2bf(v);
      } else {
        const int b = row >> 11, s = row & (SEQ - 1);
        vtout[b * (DH * SEQ) + (c - 128) * SEQ + s] = f2bf(v);
      }
    }
  }
}

// ---------------------------------------------------------------------------
// Kernel 2: split-KV causal flash (R9 verbatim; nck=4/cht=8 proven best).
// ---------------------------------------------------------------------------
__global__ __launch_bounds__(256) void flash_kernel(
    const short* __restrict__ qin, const short* __restrict__ kin,
    const short* __restrict__ vtin, float* __restrict__ po,
    float* __restrict__ pm, float* __restrict__ pl,
    const int nck, const int cht)
{
  __shared__ short k_lds[2][64][72];
  __shared__ short vt_lds[2][64][72];
  __shared__ short p_lds[4][16][72];

  const int qt = blockIdx.x;
  const int ck = blockIdx.y;
  const int t0 = ck * cht;
  if (t0 > qt) return;
  const int b = blockIdx.z;

  const int t = threadIdx.x;
  const int l = t & 63;
  const int w = t >> 6;
  const int q0 = qt * 64;
  const int tend = min(t0 + cht, qt + 1);

  const short* qb = qin  + (size_t)b * SEQ * DH;
  const short* kb = kin  + (size_t)b * SEQ * DH;
  const short* vb = vtin + (size_t)b * DH * SEQ;

  const short* qr = qb + (size_t)(q0 + w * 16 + (l & 15)) * DH + ((l >> 4) << 3);
  const bf16x8 qf0 = *(const bf16x8*)qr;
  const bf16x8 qf1 = *(const bf16x8*)(qr + 32);

  f32x4 o[4];
#pragma unroll
  for (int i = 0; i < 4; i++) o[i] = (f32x4){0.f, 0.f, 0.f, 0.f};
  float m_run[4] = {-1e30f, -1e30f, -1e30f, -1e30f};
  float l_run[4] = {0.f, 0.f, 0.f, 0.f};

  const int sr = t >> 3;
  const int sc = (t & 7) * 8;

  {
    const int j0 = t0 * 64;
#pragma unroll
    for (int i = 0; i < 2; i++) {
      const int r = sr + i * 32;
      *(bf16x8*)&k_lds[0][r][sc]  = *(const bf16x8*)(kb + (size_t)(j0 + r) * DH + sc);
      *(bf16x8*)&vt_lds[0][r][sc] = *(const bf16x8*)(vb + (size_t)r * SEQ + j0 + sc);
    }
  }
  __syncthreads();

  for (int tt = t0; tt < tend; tt++) {
    const int bi = (tt - t0) & 1;
    const int j0 = tt * 64;
    const bool pf = (tt + 1 < tend);

    bf16x8 kpf0, kpf1, vpf0, vpf1;
    if (pf) {
      const int j1 = j0 + 64;
      kpf0 = *(const bf16x8*)(kb + (size_t)(j1 + sr) * DH + sc);
      kpf1 = *(const bf16x8*)(kb + (size_t)(j1 + sr + 32) * DH + sc);
      vpf0 = *(const bf16x8*)(vb + (size_t)sr * SEQ + j1 + sc);
      vpf1 = *(const bf16x8*)(vb + (size_t)(sr + 32) * SEQ + j1 + sc);
    }

    f32x4 s[4];
#pragma unroll
    for (int nf = 0; nf < 4; nf++) {
      const short* kr = &k_lds[bi][nf * 16 + (l & 15)][(l >> 4) << 3];
      bf16x8 b0 = *(const bf16x8*)kr;
      bf16x8 b1 = *(const bf16x8*)(kr + 32);
      f32x4 a = (f32x4){0.f, 0.f, 0.f, 0.f};
      a = __builtin_amdgcn_mfma_f32_16x16x32_bf16(qf0, b0, a, 0, 0, 0);
      a = __builtin_amdgcn_mfma_f32_16x16x32_bf16(qf1, b1, a, 0, 0, 0);
      s[nf] = a;
    }

    {
      const int growb = q0 + w * 16 + ((l >> 4) << 2);
#pragma unroll
      for (int nf = 0; nf < 4; nf++) {
        const int gcol = j0 + nf * 16 + (l & 15);
#pragma unroll
        for (int j = 0; j < 4; j++)
          if (gcol > growb + j) s[nf][j] = -1e30f;
      }
    }

    float alpha[4];
#pragma unroll
    for (int j = 0; j < 4; j++) {
      float tm = fmaxf(fmaxf(s[0][j], s[1][j]), fmaxf(s[2][j], s[3][j]));
      tm = fmaxf(tm, __shfl_xor(tm, 1));
      tm = fmaxf(tm, __shfl_xor(tm, 2));
      tm = fmaxf(tm, __shfl_xor(tm, 4));
      tm = fmaxf(tm, __shfl_xor(tm, 8));
      const float mn = fmaxf(m_run[j], tm);
      alpha[j] = exp2f((m_run[j] - mn) * 1.44269504f);
      m_run[j] = mn;
      float rs = 0.f;
#pragma unroll
      for (int nf = 0; nf < 4; nf++) {
        const float p = exp2f((s[nf][j] - mn) * 1.44269504f);
        s[nf][j] = p;
        rs += p;
      }
      rs += __shfl_xor(rs, 1);
      rs += __shfl_xor(rs, 2);
      rs += __shfl_xor(rs, 4);
      rs += __shfl_xor(rs, 8);
      l_run[j] = l_run[j] * alpha[j] + rs;
    }
#pragma unroll
    for (int df = 0; df < 4; df++)
#pragma unroll
      for (int j = 0; j < 4; j++) o[df][j] *= alpha[j];

#pragma unroll
    for (int nf = 0; nf < 4; nf++)
#pragma unroll
      for (int j = 0; j < 4; j++)
        p_lds[w][((l >> 4) << 2) + j][nf * 16 + (l & 15)] = f2bf(s[nf][j]);

    asm volatile("s_waitcnt lgkmcnt(0)" ::: "memory");
    __builtin_amdgcn_sched_barrier(0);

#pragma unroll
    for (int ks = 0; ks < 2; ks++) {
      const short* pr = &p_lds[w][l & 15][ks * 32 + ((l >> 4) << 3)];
      const bf16x8 pa = *(const bf16x8*)pr;
#pragma unroll
      for (int df = 0; df < 4; df++) {
        const short* vr = &vt_lds[bi][df * 16 + (l & 15)][ks * 32 + ((l >> 4) << 3)];
        const bf16x8 vf = *(const bf16x8*)vr;
        o[df] = __builtin_amdgcn_mfma_f32_16x16x32_bf16(pa, vf, o[df], 0, 0, 0);
      }
    }

    if (pf) {
      *(bf16x8*)&k_lds[bi ^ 1][sr][sc]       = kpf0;
      *(bf16x8*)&k_lds[bi ^ 1][sr + 32][sc]  = kpf1;
      *(bf16x8*)&vt_lds[bi ^ 1][sr][sc]      = vpf0;
      *(bf16x8*)&vt_lds[bi ^ 1][sr + 32][sc] = vpf1;
    }
    __syncthreads();
  }

  const int rowb = q0 + w * 16 + ((l >> 4) << 2);
#pragma unroll
  for (int j = 0; j < 4; j++) {
    const size_t rowg = (size_t)b * SEQ + rowb + j;
#pragma unroll
    for (int df = 0; df < 4; df++)
      po[(rowg * nck + ck) * DH + df * 16 + (l & 15)] = o[df][j];
    if ((l & 15) == 0) {
      pm[rowg * nck + ck] = m_run[j];
      pl[rowg * nck + ck] = l_run[j];
    }
  }
}

// ---------------------------------------------------------------------------
// Kernel 3: merge partials (unchanged). ckshift = log2(cht*64).
// ---------------------------------------------------------------------------
__global__ __launch_bounds__(256) void merge_kernel(
    const float* __restrict__ po, const float* __restrict__ pm,
    const float* __restrict__ pl, float* __restrict__ out,
    const int nck, const int ckshift)
{
  const int gid = blockIdx.x * 256 + threadIdx.x;
  const int r = gid >> 6;
  const int d = gid & 63;
  const int s = r & (SEQ - 1);
  const int C = (s >> ckshift) + 1;

  float m = -1e30f;
  for (int c = 0; c < C; c++) m = fmaxf(m, pm[r * nck + c]);
  float den = 0.f, num = 0.f;
  for (int c = 0; c < C; c++) {
    const float wgt = exp2f((pm[r * nck + c] - m) * 1.44269504f);
    den += pl[r * nck + c] * wgt;
    num += po[(size_t)(r * nck + c) * DH + d] * wgt;
  }
  out[gid] = num / den;
}

extern "C" void kernel_launch(void* const* d_in, const int* in_sizes, int n_in,
                              void* d_out, int out_size, void* d_ws, size_t ws_size,
                              hipStream_t stream) {
  const float* X  = (const float*)d_in[0];
  const float* Wq = (const float*)d_in[1];
  const float* Wk = (const float*)d_in[2];
  const float* Wv = (const float*)d_in[3];

  const size_t nrow = (size_t)NB * SEQ;              // 8192
  short* qws  = (short*)d_ws;                        // [8192][64] bf16
  short* kws  = qws + nrow * DH;
  short* vtws = kws + nrow * DH;
  const size_t qkv_bytes = 3 * nrow * DH * sizeof(short);   // 3.15 MB

  // Big layout: qkv | pacc [4][8192][192] bf16 (12.58MB) | wbf (0.39MB)
  //   flash's po/pm/pl (8.65MB) alias the dead pacc region afterwards.
  // Need 16.12 MB (same as R11, which ran this path successfully).
  const size_t big_need = qkv_bytes + 4 * nrow * 192 * sizeof(short)
                        + 192 * DM * sizeof(short);

  if (ws_size >= big_need) {
    short* pacc = vtws + nrow * DH;
    short* wbf  = pacc + 4 * nrow * 192;
    float* po   = (float*)pacc;
    float* pm   = po + nrow * 4 * DH;
    float* pl   = pm + nrow * 4;

    wconv_kernel<<<dim3(96), 256, 0, stream>>>(Wq, Wk, Wv, wbf);
    proj_v5_kernel<<<dim3(64, 4), 512, 0, stream>>>(X, wbf, pacc);
    reduce4_kernel<<<dim3((int)(nrow * 48 / 256)), 256, 0, stream>>>(pacc, qws, kws, vtws);
    flash_kernel<<<dim3(SEQ / 64, 4, NB), 256, 0, stream>>>(qws, kws, vtws, po, pm, pl, 4, 8);
    merge_kernel<<<dim3(NB * SEQ * DH / 256), 256, 0, stream>>>(po, pm, pl, (float*)d_out, 4, 9);
  } else {
    // R9-proven fallback: qkv | po/pm/pl (wbf aliases po start)
    float* po  = (float*)(vtws + nrow * DH);
    short* wbf = (short*)po;

    int nck, cht, ckshift;
    const size_t need4 = qkv_bytes + nrow * 4 * (DH + 2) * sizeof(float);
    if (ws_size >= need4) { nck = 4; cht = 8;  ckshift = 9;  }
    else                  { nck = 1; cht = 32; ckshift = 11; }
    float* pm = po + nrow * nck * DH;
    float* pl = pm + nrow * nck;

    wconv_kernel<<<dim3(96), 256, 0, stream>>>(Wq, Wk, Wv, wbf);
    proj_fb_kernel<<<dim3(NB * SEQ / 32), 512, 0, stream>>>(X, wbf, qws, kws, vtws);
    flash_kernel<<<dim3(SEQ / 64, nck, NB), 256, 0, stream>>>(qws, kws, vtws, po, pm, pl, nck, cht);
    merge_kernel<<<dim3(NB * SEQ * DH / 256), 256, 0, stream>>>(po, pm, pl, (float*)d_out, nck, ckshift);
  }
}

// Round 18
// 48.219 us; speedup vs baseline: 1.1399x; 1.1299x over previous
//
#include <hip/hip_runtime.h>
#include <hip/hip_bf16.h>

// Problem constants
#define NB 4
#define SEQ 2048
#define DM 1024
#define DH 64

typedef __attribute__((ext_vector_type(8))) short bf16x8;
typedef __attribute__((ext_vector_type(4))) float f32x4;
typedef __attribute__((ext_vector_type(4))) short short4v;

__device__ inline short f2bf(float f) {
  union { float f; unsigned u; } x; x.f = f;
  unsigned r = x.u + 0x7FFFu + ((x.u >> 16) & 1u);
  return (short)(r >> 16);
}

// ---------------------------------------------------------------------------
// Kernel 0: W fp32 -> bf16, once. wbf[192][1024]: rows 0-63 Wq, 64-127 Wk,
// 128-191 Wv.  (R9 verbatim)
// ---------------------------------------------------------------------------
__global__ __launch_bounds__(256) void wconv_kernel(
    const float* __restrict__ Wq, const float* __restrict__ Wk,
    const float* __restrict__ Wv, short* __restrict__ wbf)
{
  const int tid = blockIdx.x * 256 + threadIdx.x;
  const int base = tid * 8;
  const int row = base >> 10;          // 0..191
  const int col = base & 1023;
  const float* src = (row < 64) ? Wq : (row < 128) ? Wk : Wv;
  src += (size_t)(row & 63) * DM + col;
  f32x4 f0 = ((const f32x4*)src)[0];
  f32x4 f1 = ((const f32x4*)src)[1];
  bf16x8 h = { f2bf(f0[0]), f2bf(f0[1]), f2bf(f0[2]), f2bf(f0[3]),
               f2bf(f1[0]), f2bf(f1[1]), f2bf(f1[2]), f2bf(f1[3]) };
  *(bf16x8*)(wbf + (size_t)row * DM + col) = h;
}

// ---------------------------------------------------------------------------
// Kernel 1: QKV projection (R9 verbatim EXCEPT the V^T epilogue: the 4
// per-reg 2B scattered stores are merged into ONE 8B short4v store —
// reg j maps to row rowb+j, consecutive in V^T's [dh][s] layout).
// Depth-2 pipelined, 256 blocks x 512 threads, 32x192 tile, BK=64, 16 iters.
// ---------------------------------------------------------------------------
__global__ __launch_bounds__(512) void proj_kernel(
    const float* __restrict__ X, const short* __restrict__ wbf,
    short* __restrict__ qout, short* __restrict__ kout,
    short* __restrict__ vtout)
{
  __shared__ short x_lds[2][32][80];
  __shared__ short w_lds[2][192][80];

  const int t = threadIdx.x;
  const int l = t & 63;
  const int w = t >> 6;                 // 0..7
  const int m0 = blockIdx.x * 32;

  f32x4 acc[3];
#pragma unroll
  for (int i = 0; i < 3; i++) acc[i] = (f32x4){0.f, 0.f, 0.f, 0.f};

  const int xr = t >> 4;                // 0..31
  const int xc = (t & 15) * 4;          // float cols 0..60
  const int wr = t >> 3;                // 0..63
  const int wc = (t & 7) * 8;           // bf16 cols 0..56

  const float* xsrc  = X   + (size_t)(m0 + xr) * DM + xc;
  const short* wsrc0 = wbf + (size_t)(wr)       * DM + wc;
  const short* wsrc1 = wbf + (size_t)(64 + wr)  * DM + wc;
  const short* wsrc2 = wbf + (size_t)(128 + wr) * DM + wc;

  // prologue: stage k-step 0 into buf0
  {
    f32x4 f = *(const f32x4*)xsrc;
    short4v h = { f2bf(f[0]), f2bf(f[1]), f2bf(f[2]), f2bf(f[3]) };
    *(short4v*)&x_lds[0][xr][xc] = h;
    *(bf16x8*)&w_lds[0][wr][wc]       = *(const bf16x8*)wsrc0;
    *(bf16x8*)&w_lds[0][64 + wr][wc]  = *(const bf16x8*)wsrc1;
    *(bf16x8*)&w_lds[0][128 + wr][wc] = *(const bf16x8*)wsrc2;
  }
  // issue k-step 1 loads into rA (in flight across the barrier)
  f32x4 xA = *(const f32x4*)(xsrc + 64);
  bf16x8 wA0 = *(const bf16x8*)(wsrc0 + 64);
  bf16x8 wA1 = *(const bf16x8*)(wsrc1 + 64);
  bf16x8 wA2 = *(const bf16x8*)(wsrc2 + 64);
  f32x4 xB;
  bf16x8 wB0, wB1, wB2;
  __syncthreads();

#pragma unroll
  for (int it = 0; it < 16; it++) {
    const int buf = it & 1;
    const int k2 = (it + 2) * 64;

    // issue loads for iter it+2 (static ping-pong: even->rB, odd->rA)
    if ((it & 1) == 0) {
      if (it + 2 < 16) {
        xB  = *(const f32x4*)(xsrc + k2);
        wB0 = *(const bf16x8*)(wsrc0 + k2);
        wB1 = *(const bf16x8*)(wsrc1 + k2);
        wB2 = *(const bf16x8*)(wsrc2 + k2);
      }
    } else {
      if (it + 2 < 16) {
        xA  = *(const f32x4*)(xsrc + k2);
        wA0 = *(const bf16x8*)(wsrc0 + k2);
        wA1 = *(const bf16x8*)(wsrc1 + k2);
        wA2 = *(const bf16x8*)(wsrc2 + k2);
      }
    }

    // compute from lds[buf]
    const short* xp = &x_lds[buf][(w & 1) * 16 + (l & 15)][(l >> 4) << 3];
    bf16x8 a0 = *(const bf16x8*)xp;
    bf16x8 a1 = *(const bf16x8*)(xp + 32);
#pragma unroll
    for (int nf = 0; nf < 3; nf++) {
      const int cf = (w >> 1) * 3 + nf;
      const short* wp = &w_lds[buf][cf * 16 + (l & 15)][(l >> 4) << 3];
      bf16x8 b0 = *(const bf16x8*)wp;
      bf16x8 b1 = *(const bf16x8*)(wp + 32);
      acc[nf] = __builtin_amdgcn_mfma_f32_16x16x32_bf16(a0, b0, acc[nf], 0, 0, 0);
      acc[nf] = __builtin_amdgcn_mfma_f32_16x16x32_bf16(a1, b1, acc[nf], 0, 0, 0);
    }

    // ds_write iter it+1's regs (issued one full iteration ago)
    if (it < 15) {
      if ((it & 1) == 0) {
        short4v h = { f2bf(xA[0]), f2bf(xA[1]), f2bf(xA[2]), f2bf(xA[3]) };
        *(short4v*)&x_lds[buf ^ 1][xr][xc] = h;
        *(bf16x8*)&w_lds[buf ^ 1][wr][wc]       = wA0;
        *(bf16x8*)&w_lds[buf ^ 1][64 + wr][wc]  = wA1;
        *(bf16x8*)&w_lds[buf ^ 1][128 + wr][wc] = wA2;
      } else {
        short4v h = { f2bf(xB[0]), f2bf(xB[1]), f2bf(xB[2]), f2bf(xB[3]) };
        *(short4v*)&x_lds[buf ^ 1][xr][xc] = h;
        *(bf16x8*)&w_lds[buf ^ 1][wr][wc]       = wB0;
        *(bf16x8*)&w_lds[buf ^ 1][64 + wr][wc]  = wB1;
        *(bf16x8*)&w_lds[buf ^ 1][128 + wr][wc] = wB2;
      }
    }
    __syncthreads();
  }

  // epilogue: C row=(lane>>4)*4+reg, col=cf*16+(lane&15)  [m89]
  const int rowb = m0 + (w & 1) * 16 + ((l >> 4) << 2);
#pragma unroll
  for (int nf = 0; nf < 3; nf++) {
    const int c = ((w >> 1) * 3 + nf) * 16 + (l & 15);
    if (c < 64) {
#pragma unroll
      for (int j = 0; j < 4; j++)
        qout[(rowb + j) * DH + c] = f2bf(acc[nf][j] * 0.03125f);  // 1/32
    } else if (c < 128) {
#pragma unroll
      for (int j = 0; j < 4; j++)
        kout[(rowb + j) * DH + (c - 64)] = f2bf(acc[nf][j]);
    } else {
      // V^T: regs j=0..3 are rows rowb..rowb+3 -> consecutive addresses in
      // [dh][s] layout; rowb%4==0 and batch boundary (2048) never crossed.
      const int b = rowb >> 11, s = rowb & (SEQ - 1);
      short4v h = { f2bf(acc[nf][0]), f2bf(acc[nf][1]),
                    f2bf(acc[nf][2]), f2bf(acc[nf][3]) };
      *(short4v*)(vtout + (size_t)b * DH * SEQ + (size_t)(c - 128) * SEQ + s) = h;
    }
  }
}

// ---------------------------------------------------------------------------
// Kernel 2: split-KV causal flash (R9 verbatim; nck=4/cht=8).
// ---------------------------------------------------------------------------
__global__ __launch_bounds__(256) void flash_kernel(
    const short* __restrict__ qin, const short* __restrict__ kin,
    const short* __restrict__ vtin, float* __restrict__ po,
    float* __restrict__ pm, float* __restrict__ pl,
    const int nck, const int cht)
{
  __shared__ short k_lds[2][64][72];
  __shared__ short vt_lds[2][64][72];
  __shared__ short p_lds[4][16][72];

  const int qt = blockIdx.x;
  const int ck = blockIdx.y;
  const int t0 = ck * cht;
  if (t0 > qt) return;
  const int b = blockIdx.z;

  const int t = threadIdx.x;
  const int l = t & 63;
  const int w = t >> 6;
  const int q0 = qt * 64;
  const int tend = min(t0 + cht, qt + 1);

  const short* qb = qin  + (size_t)b * SEQ * DH;
  const short* kb = kin  + (size_t)b * SEQ * DH;
  const short* vb = vtin + (size_t)b * DH * SEQ;

  const short* qr = qb + (size_t)(q0 + w * 16 + (l & 15)) * DH + ((l >> 4) << 3);
  const bf16x8 qf0 = *(const bf16x8*)qr;
  const bf16x8 qf1 = *(const bf16x8*)(qr + 32);

  f32x4 o[4];
#pragma unroll
  for (int i = 0; i < 4; i++) o[i] = (f32x4){0.f, 0.f, 0.f, 0.f};
  float m_run[4] = {-1e30f, -1e30f, -1e30f, -1e30f};
  float l_run[4] = {0.f, 0.f, 0.f, 0.f};

  const int sr = t >> 3;
  const int sc = (t & 7) * 8;

  {
    const int j0 = t0 * 64;
#pragma unroll
    for (int i = 0; i < 2; i++) {
      const int r = sr + i * 32;
      *(bf16x8*)&k_lds[0][r][sc]  = *(const bf16x8*)(kb + (size_t)(j0 + r) * DH + sc);
      *(bf16x8*)&vt_lds[0][r][sc] = *(const bf16x8*)(vb + (size_t)r * SEQ + j0 + sc);
    }
  }
  __syncthreads();

  for (int tt = t0; tt < tend; tt++) {
    const int bi = (tt - t0) & 1;
    const int j0 = tt * 64;
    const bool pf = (tt + 1 < tend);

    bf16x8 kpf0, kpf1, vpf0, vpf1;
    if (pf) {
      const int j1 = j0 + 64;
      kpf0 = *(const bf16x8*)(kb + (size_t)(j1 + sr) * DH + sc);
      kpf1 = *(const bf16x8*)(kb + (size_t)(j1 + sr + 32) * DH + sc);
      vpf0 = *(const bf16x8*)(vb + (size_t)sr * SEQ + j1 + sc);
      vpf1 = *(const bf16x8*)(vb + (size_t)(sr + 32) * SEQ + j1 + sc);
    }

    f32x4 s[4];
#pragma unroll
    for (int nf = 0; nf < 4; nf++) {
      const short* kr = &k_lds[bi][nf * 16 + (l & 15)][(l >> 4) << 3];
      bf16x8 b0 = *(const bf16x8*)kr;
      bf16x8 b1 = *(const bf16x8*)(kr + 32);
      f32x4 a = (f32x4){0.f, 0.f, 0.f, 0.f};
      a = __builtin_amdgcn_mfma_f32_16x16x32_bf16(qf0, b0, a, 0, 0, 0);
      a = __builtin_amdgcn_mfma_f32_16x16x32_bf16(qf1, b1, a, 0, 0, 0);
      s[nf] = a;
    }

    {
      const int growb = q0 + w * 16 + ((l >> 4) << 2);
#pragma unroll
      for (int nf = 0; nf < 4; nf++) {
        const int gcol = j0 + nf * 16 + (l & 15);
#pragma unroll
        for (int j = 0; j < 4; j++)
          if (gcol > growb + j) s[nf][j] = -1e30f;
      }
    }

    float alpha[4];
#pragma unroll
    for (int j = 0; j < 4; j++) {
      float tm = fmaxf(fmaxf(s[0][j], s[1][j]), fmaxf(s[2][j], s[3][j]));
      tm = fmaxf(tm, __shfl_xor(tm, 1));
      tm = fmaxf(tm, __shfl_xor(tm, 2));
      tm = fmaxf(tm, __shfl_xor(tm, 4));
      tm = fmaxf(tm, __shfl_xor(tm, 8));
      const float mn = fmaxf(m_run[j], tm);
      alpha[j] = exp2f((m_run[j] - mn) * 1.44269504f);
      m_run[j] = mn;
      float rs = 0.f;
#pragma unroll
      for (int nf = 0; nf < 4; nf++) {
        const float p = exp2f((s[nf][j] - mn) * 1.44269504f);
        s[nf][j] = p;
        rs += p;
      }
      rs += __shfl_xor(rs, 1);
      rs += __shfl_xor(rs, 2);
      rs += __shfl_xor(rs, 4);
      rs += __shfl_xor(rs, 8);
      l_run[j] = l_run[j] * alpha[j] + rs;
    }
#pragma unroll
    for (int df = 0; df < 4; df++)
#pragma unroll
      for (int j = 0; j < 4; j++) o[df][j] *= alpha[j];

#pragma unroll
    for (int nf = 0; nf < 4; nf++)
#pragma unroll
      for (int j = 0; j < 4; j++)
        p_lds[w][((l >> 4) << 2) + j][nf * 16 + (l & 15)] = f2bf(s[nf][j]);

    asm volatile("s_waitcnt lgkmcnt(0)" ::: "memory");
    __builtin_amdgcn_sched_barrier(0);

#pragma unroll
    for (int ks = 0; ks < 2; ks++) {
      const short* pr = &p_lds[w][l & 15][ks * 32 + ((l >> 4) << 3)];
      const bf16x8 pa = *(const bf16x8*)pr;
#pragma unroll
      for (int df = 0; df < 4; df++) {
        const short* vr = &vt_lds[bi][df * 16 + (l & 15)][ks * 32 + ((l >> 4) << 3)];
        const bf16x8 vf = *(const bf16x8*)vr;
        o[df] = __builtin_amdgcn_mfma_f32_16x16x32_bf16(pa, vf, o[df], 0, 0, 0);
      }
    }

    if (pf) {
      *(bf16x8*)&k_lds[bi ^ 1][sr][sc]       = kpf0;
      *(bf16x8*)&k_lds[bi ^ 1][sr + 32][sc]  = kpf1;
      *(bf16x8*)&vt_lds[bi ^ 1][sr][sc]      = vpf0;
      *(bf16x8*)&vt_lds[bi ^ 1][sr + 32][sc] = vpf1;
    }
    __syncthreads();
  }

  const int rowb = q0 + w * 16 + ((l >> 4) << 2);
#pragma unroll
  for (int j = 0; j < 4; j++) {
    const size_t rowg = (size_t)b * SEQ + rowb + j;
#pragma unroll
    for (int df = 0; df < 4; df++)
      po[(rowg * nck + ck) * DH + df * 16 + (l & 15)] = o[df][j];
    if ((l & 15) == 0) {
      pm[rowg * nck + ck] = m_run[j];
      pl[rowg * nck + ck] = l_run[j];
    }
  }
}

// ---------------------------------------------------------------------------
// Kernel 3: merge partials (R9 verbatim). ckshift = log2(cht*64).
// ---------------------------------------------------------------------------
__global__ __launch_bounds__(256) void merge_kernel(
    const float* __restrict__ po, const float* __restrict__ pm,
    const float* __restrict__ pl, float* __restrict__ out,
    const int nck, const int ckshift)
{
  const int gid = blockIdx.x * 256 + threadIdx.x;
  const int r = gid >> 6;
  const int d = gid & 63;
  const int s = r & (SEQ - 1);
  const int C = (s >> ckshift) + 1;

  float m = -1e30f;
  for (int c = 0; c < C; c++) m = fmaxf(m, pm[r * nck + c]);
  float den = 0.f, num = 0.f;
  for (int c = 0; c < C; c++) {
    const float wgt = exp2f((pm[r * nck + c] - m) * 1.44269504f);
    den += pl[r * nck + c] * wgt;
    num += po[(size_t)(r * nck + c) * DH + d] * wgt;
  }
  out[gid] = num / den;
}

extern "C" void kernel_launch(void* const* d_in, const int* in_sizes, int n_in,
                              void* d_out, int out_size, void* d_ws, size_t ws_size,
                              hipStream_t stream) {
  const float* X  = (const float*)d_in[0];
  const float* Wq = (const float*)d_in[1];
  const float* Wk = (const float*)d_in[2];
  const float* Wv = (const float*)d_in[3];

  const size_t nrow = (size_t)NB * SEQ;              // 8192
  short* qws  = (short*)d_ws;                        // [8192][64] bf16
  short* kws  = qws + nrow * DH;
  short* vtws = kws + nrow * DH;
  const size_t qkv_bytes = 3 * nrow * DH * sizeof(short);   // 3.15 MB

  // layout: qkv | po [8192][nck][64] f32 | pm | pl   (wbf aliases po start;
  // wbf is dead before flash overwrites it)
  int nck, cht, ckshift;
  {
    const size_t need4 = qkv_bytes + nrow * 4 * (DH + 2) * sizeof(float);
    if (ws_size >= need4) { nck = 4; cht = 8;  ckshift = 9;  }
    else                  { nck = 1; cht = 32; ckshift = 11; }
  }
  float* po  = (float*)(vtws + nrow * DH);
  short* wbf = (short*)po;
  float* pm  = po + nrow * nck * DH;
  float* pl  = pm + nrow * nck;

  wconv_kernel<<<dim3(96), 256, 0, stream>>>(Wq, Wk, Wv, wbf);
  proj_kernel<<<dim3(NB * SEQ / 32), 512, 0, stream>>>(X, wbf, qws, kws, vtws);
  flash_kernel<<<dim3(SEQ / 64, nck, NB), 256, 0, stream>>>(qws, kws, vtws, po, pm, pl, nck, cht);
  merge_kernel<<<dim3(NB * SEQ * DH / 256), 256, 0, stream>>>(po, pm, pl, (float*)d_out, nck, ckshift);
}